// Round 11
// baseline (279.855 us; speedup 1.0000x reference)
//
#include <hip/hip_runtime.h>

namespace {
constexpr int kS   = 1024;
constexpr int kD   = 512;
constexpr int kDFF = 2048;
constexpr int kNF  = 85;   // D//6
}

typedef __attribute__((ext_vector_type(8))) short bhalf8_t;    // 8x16-bit in 4 VGPRs
typedef _Float16 half8_t __attribute__((ext_vector_type(8)));
typedef __attribute__((ext_vector_type(4))) float f32x4_t;

// ---------------- helpers ----------------
__device__ __forceinline__ float wave_sum(float v) {
#pragma unroll
    for (int o = 1; o < 64; o <<= 1) v += __shfl_xor(v, o, 64);
    return v;
}
__device__ __forceinline__ unsigned short f2h(float f) {    // RNE fp32->fp16
    _Float16 h = (_Float16)f;
    return __builtin_bit_cast(unsigned short, h);
}
__device__ __forceinline__ float h2f(unsigned short u) {
    return (float)__builtin_bit_cast(_Float16, u);
}

// ---- 32x32 f32->f16 transpose tile helper ----
__device__ __forceinline__ void tr_tile32(const float* __restrict__ in,
                                          unsigned short* __restrict__ out,
                                          int N, int K, int k0, int n0, int t,
                                          float* tile /*32*33*/)
{
    int r = t >> 3, c4 = (t & 7) * 4;
    float4 v = *reinterpret_cast<const float4*>(&in[(long)(k0 + r) * N + n0 + c4]);
    tile[r * 33 + c4] = v.x; tile[r * 33 + c4 + 1] = v.y;
    tile[r * 33 + c4 + 2] = v.z; tile[r * 33 + c4 + 3] = v.w;
    __syncthreads();
    int nr = t >> 3, kq = (t & 7) * 4;
    unsigned short h[4];
#pragma unroll
    for (int j = 0; j < 4; ++j) h[j] = f2h(tile[(kq + j) * 33 + nr]);
    *reinterpret_cast<ushort4*>(&out[(long)(n0 + nr) * K + k0 + kq]) =
        make_ushort4(h[0], h[1], h[2], h[3]);
}

// ======= single preamble: input_pe(8-row) | transposes | pwl_tab+sort ============
// block ranges: [0,128) input_pe; [128,6272) transposes; [6272,6530) pwl_tab.
__global__ __launch_bounds__(256)
void prep_k(const float* __restrict__ feat, const float* __restrict__ pos,
            const float* __restrict__ fb, const float* __restrict__ in_w,
            const float* __restrict__ in_b, float* __restrict__ x,
            unsigned short* __restrict__ xb,
            const float* __restrict__ qw, const float* __restrict__ kw,
            const float* __restrict__ vw, const float* __restrict__ ow,
            unsigned short* __restrict__ qwb, unsigned short* __restrict__ kwb,
            unsigned short* __restrict__ vwb, unsigned short* __restrict__ owb,
            const float* __restrict__ f1w, unsigned short* __restrict__ f1wb,
            const float* __restrict__ f2w, unsigned short* __restrict__ f2wb,
            const float* __restrict__ a_, const float* __restrict__ b_,
            const float* __restrict__ w2, const float* __restrict__ b2,
            float* __restrict__ bp_out, float* __restrict__ Atab,
            float* __restrict__ Btab)
{
    __shared__ float smem[1056];
    int bid = blockIdx.x;
    int t = threadIdx.x;
    if (bid < 128) {
        // ---- input projection + PE, 8 rows/block (in_w traffic 32MB -> 16MB) ----
        int s0 = bid * 8;
        smem[t]       = feat[s0 * 64 + t];
        smem[256 + t] = feat[s0 * 64 + 256 + t];   // 8 rows x 64 feat
        __syncthreads();
        float b0 = in_b[t], b1 = in_b[t + 256];
        float a0[8], a1[8];
#pragma unroll
        for (int r = 0; r < 8; ++r) { a0[r] = b0; a1[r] = b1; }
#pragma unroll 4
        for (int c = 0; c < 64; ++c) {
            float w0 = in_w[c * kD + t], w1 = in_w[c * kD + 256 + t];
#pragma unroll
            for (int r = 0; r < 8; ++r) {
                a0[r] = fmaf(smem[r * 64 + c], w0, a0[r]);
                a1[r] = fmaf(smem[r * 64 + c], w1, a1[r]);
            }
        }
#pragma unroll
        for (int r = 0; r < 8; ++r) {
            int s = s0 + r;
            float pe0 = 0.f, pe1 = 0.f;
            int d = t;
            if (d < 6 * kNF) {
                int seg = d / kNF, idx = d - seg * kNF;
                float cs = pos[s * 3 + (seg >> 1)] * fb[idx];
                pe0 = (seg & 1) ? cosf(cs) : sinf(cs);
            }
            d = t + 256;
            if (d < 6 * kNF) {
                int seg = d / kNF, idx = d - seg * kNF;
                float cs = pos[s * 3 + (seg >> 1)] * fb[idx];
                pe1 = (seg & 1) ? cosf(cs) : sinf(cs);
            }
            float o0 = a0[r] + pe0, o1 = a1[r] + pe1;
            x[s * kD + t]        = o0;
            x[s * kD + 256 + t]  = o1;
            xb[s * kD + t]       = f2h(o0);
            xb[s * kD + 256 + t] = f2h(o1);
        }
    } else if (bid < 6272) {
        // ---- weight transposes ----
        int idx = bid - 128;
        if (idx < 2048) {
            int zz = idx >> 8, rem = idx & 255;
            int mat = zz >> 1, layer = zz & 1;
            const float* in = (mat == 0) ? qw : (mat == 1) ? kw : (mat == 2) ? vw : ow;
            unsigned short* out = (mat == 0) ? qwb : (mat == 1) ? kwb : (mat == 2) ? vwb : owb;
            tr_tile32(in + (long)layer * 262144, out + (long)layer * 262144,
                      512, 512, (rem & 15) * 32, (rem >> 4) * 32, t, smem);
        } else if (idx < 4096) {
            int l = idx - 2048;
            int z = l >> 10;
            tr_tile32(f1w + (long)z * 1048576, f1wb + (long)z * 1048576,
                      2048, 512, (l & 15) * 32, ((l >> 4) & 63) * 32, t, smem);
        } else {
            int l = idx - 4096;
            int z = l >> 10;
            tr_tile32(f2w + (long)z * 1048576, f2wb + (long)z * 1048576,
                      512, 2048, (l & 63) * 32, ((l >> 6) & 15) * 32, t, smem);
        }
    } else {
        // ---- pwl_tab with local breakpoint sort: 129 segs x 2 layers ----
        int l = bid - 6272;
        int seg = l % 129, ly = l / 129;
        const float* ap = a_ + ly * 128;
        const float* bpp = b_ + ly * 128;
        const float* w2p = w2 + ly * 1024;
        const float* b2p = b2 + ly * 8;
        float* At = Atab + ly * 1040;
        float* Bt = Btab + ly * 1040;

        if (t < 128) {
            float a = ap[t], b = bpp[t];
            smem[t] = (a != 0.f) ? (-b / a) : 3.0e38f;
        }
        __syncthreads();
        for (int ksz = 2; ksz <= 128; ksz <<= 1) {
            for (int j = ksz >> 1; j > 0; j >>= 1) {
                if (t < 128) {
                    int ixj = t ^ j;
                    if (ixj > t) {
                        bool up = ((t & ksz) == 0);
                        float x0 = smem[t], x1 = smem[ixj];
                        if ((x0 > x1) == up) { smem[t] = x1; smem[ixj] = x0; }
                    }
                }
                __syncthreads();
            }
        }
        float m;
        if (seg == 0)        m = smem[0] - 1.0f;
        else if (seg == 128) m = smem[127] + 1.0f;
        else                 m = 0.5f * (smem[seg - 1] + smem[seg]);
        if (seg == 0 && t < 128) bp_out[ly * 128 + t] = smem[t];  // for biasmap
        __syncthreads();                       // all reads of keys done

        int h = t & 7, cg = t >> 3;
        float A = 0.f, B = 0.f;
#pragma unroll
        for (int j = 0; j < 4; ++j) {
            int c = cg * 4 + j;
            float a = ap[c], b = bpp[c];
            if (fmaf(a, m, b) > 0.f) {
                float w = w2p[c * 8 + h];
                A = fmaf(a, w, A);
                B = fmaf(b, w, B);
            }
        }
#pragma unroll
        for (int off = 8; off < 64; off <<= 1) {
            A += __shfl_xor(A, off, 64);
            B += __shfl_xor(B, off, 64);
        }
        int w = t >> 6, lane = t & 63;
        if (lane < 8) { smem[w * 8 + lane] = A; smem[32 + w * 8 + lane] = B; }
        __syncthreads();
        if (t < 8) {
            float At_ = smem[t] + smem[8 + t] + smem[16 + t] + smem[24 + t];
            float Bt_ = smem[32 + t] + smem[40 + t] + smem[48 + t] + smem[56 + t];
            At[seg * 8 + t] = At_;
            Bt[seg * 8 + t] = Bt_ + b2p[t];
        }
    }
}

// ====== GEMM core v3: global_load_lds + XOR swizzle + COUNTED vmcnt (T4) =========
constexpr int ASZ2 = 64 * 64;     // shorts per A buffer (8KB)
constexpr int BSZ2 = 128 * 64;    // shorts per B buffer (16KB)

// old-stride constants kept for the O-proj custom path + V-transpose region
constexpr int BKp = 72;
constexpr int ASZ = 64 * BKp;
constexpr int BSZ = 128 * BKp;

__device__ __forceinline__ void gload16(const unsigned short* g, unsigned short* l) {
    __builtin_amdgcn_global_load_lds(
        (const __attribute__((address_space(1))) unsigned int*)g,
        (__attribute__((address_space(3))) unsigned int*)l, 16, 0, 0);
}

template<int K>
__device__ __forceinline__ void gemm_core(
    const unsigned short* __restrict__ Ap, const unsigned short* __restrict__ Bp,
    int lda, int ldb, int bm, int bn, int tid,
    unsigned short* __restrict__ As, unsigned short* __restrict__ Bs,
    f32x4_t acc[2][4])
{
    int w = tid >> 6, lane = tid & 63, quad = lane >> 4, l16 = lane & 15;
    int wm = (w >> 1) * 32, wn = (w & 1) * 64;
    int lr = lane >> 3;              // row within 8-row group (== row&7)
    int sw = (lane & 7) ^ lr;        // logical col16 fetched into physical slot lane&7

    const unsigned short* pa  = Ap + (long)(bm + w * 16 + lr) * lda + sw * 8;
    const unsigned short* pa2 = pa + (long)8 * lda;
    const unsigned short* pb  = Bp + (long)(bn + w * 32 + lr) * ldb + sw * 8;

    auto stage = [&](int t) {
        int buf = t % 3;
        unsigned short* as = As + buf * ASZ2 + w * 16 * 64;
        unsigned short* bs = Bs + buf * BSZ2 + w * 32 * 64;
        int k0 = t * 64;
        gload16(pa + k0, as);
        gload16(pa2 + k0, as + 8 * 64);
#pragma unroll
        for (int j = 0; j < 4; ++j)
            gload16(pb + (long)(j * 8) * ldb + k0, bs + j * 8 * 64);
    };

    constexpr int NT = K / 64;
    stage(0);
    if (NT > 1) stage(1);
    int r7 = l16 & 7;
#pragma unroll
    for (int t = 0; t < NT; ++t) {
        // wait until stage(t) landed; stage(t+1)'s 6 loads may stay outstanding
        if (t + 1 < NT) asm volatile("s_waitcnt vmcnt(6)" ::: "memory");
        else            asm volatile("s_waitcnt vmcnt(0)" ::: "memory");
        __builtin_amdgcn_s_barrier();
        __builtin_amdgcn_sched_barrier(0);
        if (t + 2 < NT) stage(t + 2);          // into buf freed at step t-1
        const unsigned short* as = As + (t % 3) * ASZ2;
        const unsigned short* bs = Bs + (t % 3) * BSZ2;
#pragma unroll
        for (int kq = 0; kq < 2; ++kq) {
            int slot = ((kq * 4 + quad) ^ r7) * 8;
            bhalf8_t af[2], bf[4];
#pragma unroll
            for (int i = 0; i < 2; ++i)
                af[i] = *reinterpret_cast<const bhalf8_t*>(
                    &as[(wm + i * 16 + l16) * 64 + slot]);
#pragma unroll
            for (int j = 0; j < 4; ++j)
                bf[j] = *reinterpret_cast<const bhalf8_t*>(
                    &bs[(wn + j * 16 + l16) * 64 + slot]);
#pragma unroll
            for (int i = 0; i < 2; ++i)
#pragma unroll
                for (int j = 0; j < 4; ++j)
                    acc[i][j] = __builtin_amdgcn_mfma_f32_16x16x32_f16(
                        __builtin_bit_cast(half8_t, af[i]), __builtin_bit_cast(half8_t, bf[j]),
                        acc[i][j], 0, 0, 0);
        }
    }
}

// ========== merged: QKV GEMM (192 blocks, first) | biasmap (1024 blocks) =========
// bmap layout is PERMUTED for vectorized flash reads:
//   element (gm, gn) stored at [h][gm][ (gn>>7)*128 + (gn&15)*8 + ((gn>>4)&7) ]
// biasmap block = one row gm; dist computed ON THE FLY from pos (bit-identical to
// the old dist_k ops); values staged in LDS, then coalesced 16B stores.
__global__ __launch_bounds__(256, 2)
void qkv_bias_k(const unsigned short* __restrict__ xb,
                const unsigned short* __restrict__ qwb, const unsigned short* __restrict__ kwb,
                const unsigned short* __restrict__ vwb,
                const float* __restrict__ qbias, const float* __restrict__ kbias,
                const float* __restrict__ vbias,
                unsigned short* __restrict__ qb2, unsigned short* __restrict__ kb2,
                unsigned short* __restrict__ vtb,
                const float* __restrict__ pos, const float* __restrict__ bp,
                const float* __restrict__ Atab, const float* __restrict__ Btab,
                unsigned short* __restrict__ bmap, unsigned int* __restrict__ cnt)
{
    __shared__ __align__(16) unsigned short smem[3 * ASZ2 + 3 * BSZ2];  // 73728 B
    int bid = blockIdx.x;
    int tid = threadIdx.x;
    if (bid < 192) {
        int z = bid >> 6, rem = bid & 63;
        int bm = (rem & 15) * 64, bn = (rem >> 4) * 128;
        const unsigned short* Bp = (z == 1) ? kwb : (z == 2) ? vwb : qwb;
        const float* bias = (z == 1) ? kbias : (z == 2) ? vbias : qbias;
        f32x4_t acc[2][4] = {};
        gemm_core<512>(xb, Bp, 512, 512, bm, bn, tid, smem, smem + 3 * ASZ2, acc);

        int w = tid >> 6, lane = tid & 63, quad = lane >> 4, l16 = lane & 15;
        int wm = (w >> 1) * 32, wn = (w & 1) * 64;
        if (z == 2) {
            // fused V transpose: write vtb[h][d][s] = f16((v+bias)*1024)
            __syncthreads();                         // all waves done with LDS
            unsigned short* T = smem;                // 128 x 72 region
#pragma unroll
            for (int j = 0; j < 4; ++j) {
                int ln = wn + j * 16 + l16;
                float bv = bias[bn + ln];
#pragma unroll
                for (int i = 0; i < 2; ++i)
#pragma unroll
                    for (int r = 0; r < 4; ++r)
                        T[ln * BKp + wm + i * 16 + quad * 4 + r] =
                            f2h((acc[i][j][r] + bv) * 1024.f);
            }
            __syncthreads();
            int nr = tid >> 1, mc = (tid & 1) * 32;
            int gn = bn + nr;
            unsigned short* dst = vtb + (long)(gn >> 6) * 65536
                                + (long)(gn & 63) * 1024 + bm + mc;
#pragma unroll
            for (int jj = 0; jj < 4; ++jj)
                *reinterpret_cast<bhalf8_t*>(dst + jj * 8) =
                    *reinterpret_cast<const bhalf8_t*>(&T[nr * BKp + mc + jj * 8]);
        } else {
#pragma unroll
            for (int j = 0; j < 4; ++j) {
                int n = bn + wn + j * 16 + l16;
                float bv = bias[n];
                unsigned short* dst = ((z == 1) ? kb2 : qb2)
                    + (long)(n >> 6) * 131072 + (n & 63);
#pragma unroll
                for (int i = 0; i < 2; ++i)
#pragma unroll
                    for (int r = 0; r < 4; ++r) {
                        int m = bm + wm + i * 16 + quad * 4 + r;
                        float s = acc[i][j][r] + bv;
                        unsigned short hi = f2h(s);
                        dst[(long)m * 128]      = hi;
                        dst[(long)m * 128 + 64] = (z == 0) ? f2h(s - h2f(hi)) : hi;
                    }
            }
        }
    } else {
        // zero the pool/head counters
        if (bid == 192 && tid < 8) cnt[tid] = 0;
        // ---- biasmap: on-the-fly dist + PWL eval -> permuted f16 map ----
        float* fs = reinterpret_cast<float*>(smem);
        float* bps = fs;            // 128 floats
        float* Ah  = fs + 128;      // 1032
        float* Bh  = fs + 1160;     // 1032  (total 2192 floats = 4384 shorts)
        unsigned short* perm = smem + 4384;              // 8704 shorts
        float* posl = reinterpret_cast<float*>(smem + 13088);  // 3072 floats
        int t = tid;
        if (t < 128) bps[t] = bp[t];
        for (int i = t; i < 1032; i += 256) { Ah[i] = Atab[i]; Bh[i] = Btab[i]; }
        for (int i = t; i < 3072; i += 256) posl[i] = pos[i];
        __syncthreads();

        long gm = bid - 192;                    // one row per block
        float px = posl[gm * 3], py = posl[gm * 3 + 1], pz = posl[gm * 3 + 2];
        int gn0 = t * 4;
        float dv[4];
        int seg[4];
#pragma unroll
        for (int j = 0; j < 4; ++j) {
            int jj = gn0 + j;
            float dx = px - posl[jj * 3];
            float dy = py - posl[jj * 3 + 1];
            float dz = pz - posl[jj * 3 + 2];
            float sq = dx * dx + dy * dy + dz * dz;
            float tv = sq > 0.f ? sqrtf(sq) : 0.f;   // identical ops to old dist_k
            dv[j] = tv;
            int lo = 0, hi = 128;
            while (lo < hi) { int mid = (lo + hi) >> 1; if (bps[mid] < tv) lo = mid + 1; else hi = mid; }
            seg[j] = lo;
        }
        int zz = gn0 >> 7, nb = (gn0 >> 4) & 7, c4 = gn0 & 15;
        int pb0 = zz * 136 + nb;
#pragma unroll
        for (int h = 0; h < 8; ++h) {
            unsigned short* ph = perm + h * 1088 + pb0;
#pragma unroll
            for (int j = 0; j < 4; ++j)
                ph[(c4 + j) * 8] =
                    f2h(fmaf(Ah[seg[j] * 8 + h], dv[j], Bh[seg[j] * 8 + h]));
        }
        __syncthreads();
        // coalesced write-out: 8192 shorts = 256 thr x 4 x bhalf8
#pragma unroll
        for (int it = 0; it < 4; ++it) {
            int idx = it * 2048 + t * 8;
            int h   = idx >> 10;
            int off = idx & 1023;
            int z2  = off >> 7, r = off & 127;
            *reinterpret_cast<bhalf8_t*>(bmap + (long)h * 1048576 + gm * 1024 + off) =
                *reinterpret_cast<const bhalf8_t*>(&perm[h * 1088 + z2 * 136 + r]);
        }
    }
}

// ---------------- FFN1 GEMM, fused bias + relu -> hb f16 ----------------
__global__ __launch_bounds__(256, 2)
void bgemm_ffn1_k(const unsigned short* __restrict__ A,
                  const unsigned short* __restrict__ B,
                  const float* __restrict__ bias,
                  unsigned short* __restrict__ hb)
{
    __shared__ __align__(16) unsigned short smem[3 * ASZ2 + 3 * BSZ2];
    int tid = threadIdx.x;
    int bm = blockIdx.x * 64, bn = blockIdx.y * 128;
    f32x4_t acc[2][4] = {};
    gemm_core<512>(A, B, 512, 512, bm, bn, tid, smem, smem + 3 * ASZ2, acc);

    int w = tid >> 6, lane = tid & 63, quad = lane >> 4, l16 = lane & 15;
    int wm = (w >> 1) * 32, wn = (w & 1) * 64;
#pragma unroll
    for (int j = 0; j < 4; ++j) {
        int n = bn + wn + j * 16 + l16;
        float bv = bias[n];
#pragma unroll
        for (int i = 0; i < 2; ++i)
#pragma unroll
            for (int r = 0; r < 4; ++r) {
                int m = bm + wm + i * 16 + quad * 4 + r;
                hb[(long)m * kDFF + n] = f2h(fmaxf(acc[i][j][r] + bv, 0.f));
            }
    }
}

// -------- split-K GEMM -> f16 partials (FFN2 K=512/split) ----
template<int K>
__global__ __launch_bounds__(256, 2)
void bgemm_k(const unsigned short* __restrict__ A, const unsigned short* __restrict__ B,
             int N, int lda, int ldb, unsigned short* __restrict__ Cpart)
{
    __shared__ __align__(16) unsigned short smem[3 * ASZ2 + 3 * BSZ2];
    int tid = threadIdx.x;
    int ks = blockIdx.z;
    const unsigned short* Ap = A + (long)ks * K;
    const unsigned short* Bp = B + (long)ks * K;
    int bm = blockIdx.x * 64, bn = blockIdx.y * 128;
    f32x4_t acc[2][4] = {};
    gemm_core<K>(Ap, Bp, lda, ldb, bm, bn, tid, smem, smem + 3 * ASZ2, acc);

    int w = tid >> 6, lane = tid & 63, quad = lane >> 4, l16 = lane & 15;
    int wm = (w >> 1) * 32, wn = (w & 1) * 64;
    unsigned short* Cp = Cpart + (long)ks * kS * N;
#pragma unroll
    for (int i = 0; i < 2; ++i)
#pragma unroll
        for (int j = 0; j < 4; ++j)
#pragma unroll
            for (int r = 0; r < 4; ++r) {
                int m = bm + wm + i * 16 + quad * 4 + r;
                int n = bn + wn + j * 16 + l16;
                Cp[(long)m * N + n] = f2h(acc[i][j][r]);
            }
}

// ------- O-proj GEMM with flash-merge fused into A-staging (BK=64 = head_dim) ----
__global__ __launch_bounds__(256, 2)
void bgemm_oproj_k(const unsigned short* __restrict__ po,
                   const float* __restrict__ pm, const float* __restrict__ pl,
                   const unsigned short* __restrict__ Bw,
                   unsigned short* __restrict__ Cpart)
{
    __shared__ __align__(16) unsigned short As[2 * ASZ];
    __shared__ __align__(16) unsigned short Bs[2 * BSZ];
    __shared__ float wz_s[2][64][9];
    __shared__ float inv_s[2][64];

    int tid = threadIdx.x;
    int ks = blockIdx.z;
    int bm = blockIdx.x * 64, bn = blockIdx.y * 128;
    int h0 = ks * 2;

    // B for both K-steps: load + stage (no barrier needed yet)
    int br = tid >> 1, bc = (tid & 1) * 32;
    {
        const unsigned short* pb = Bw + (long)(bn + br) * 512 + ks * 128 + bc;
#pragma unroll
        for (int t = 0; t < 2; ++t) {
            bhalf8_t v0 = *reinterpret_cast<const bhalf8_t*>(pb + t * 64);
            bhalf8_t v1 = *reinterpret_cast<const bhalf8_t*>(pb + t * 64 + 8);
            bhalf8_t v2 = *reinterpret_cast<const bhalf8_t*>(pb + t * 64 + 16);
            bhalf8_t v3 = *reinterpret_cast<const bhalf8_t*>(pb + t * 64 + 24);
            unsigned short* bs = Bs + t * BSZ;
            *reinterpret_cast<bhalf8_t*>(&bs[br * BKp + bc])      = v0;
            *reinterpret_cast<bhalf8_t*>(&bs[br * BKp + bc + 8])  = v1;
            *reinterpret_cast<bhalf8_t*>(&bs[br * BKp + bc + 16]) = v2;
            *reinterpret_cast<bhalf8_t*>(&bs[br * BKp + bc + 24]) = v3;
        }
    }

    // softmax-merge weights for (step, row): tid<128 -> (t = tid>>6, r = tid&63)
    if (tid < 128) {
        int t = tid >> 6, r = tid & 63;
        long sidx = (long)(h0 + t) * 1024 + bm + r;
        float m[8], M = -3.0e38f;
#pragma unroll
        for (int z = 0; z < 8; ++z) { m[z] = pm[z * 8192 + sidx]; M = fmaxf(M, m[z]); }
        float lt = 0.f;
#pragma unroll
        for (int z = 0; z < 8; ++z) {
            float w = __expf(m[z] - M);
            wz_s[t][r][z] = w;
            lt = fmaf(pl[z * 8192 + sidx], w, lt);
        }
        inv_s[t][r] = 1.f / lt;
    }
    __syncthreads();                              // wz_s/inv_s visible

    // A merge-stage both steps: coalesced po reads (4 threads = one 128B row)
    int ar = tid >> 2, ac = (tid & 3) * 16;
#pragma unroll
    for (int t = 0; t < 2; ++t) {
        float inv = inv_s[t][ar];
        const unsigned short* p = po + ((long)(h0 + t) * 1024 + bm + ar) * 64 + ac;
        float acc[16] = {};
#pragma unroll
        for (int z = 0; z < 8; ++z) {
            float w = wz_s[t][ar][z];
            bhalf8_t v0 = *reinterpret_cast<const bhalf8_t*>(p + (long)z * 524288);
            bhalf8_t v1 = *reinterpret_cast<const bhalf8_t*>(p + (long)z * 524288 + 8);
#pragma unroll
            for (int j = 0; j < 8; ++j) {
                acc[j]     = fmaf(h2f((unsigned short)v0[j]), w, acc[j]);
                acc[8 + j] = fmaf(h2f((unsigned short)v1[j]), w, acc[8 + j]);
            }
        }
        unsigned short* as = As + t * ASZ;
#pragma unroll
        for (int j = 0; j < 16; ++j)
            as[ar * BKp + ac + j] = f2h(acc[j] * inv);
    }
    __syncthreads();                              // As/Bs ready (both steps)

    // MFMA over both steps, no further barriers
    int w = tid >> 6, lane = tid & 63, quad = lane >> 4, l16 = lane & 15;
    int wm = (w >> 1) * 32, wn = (w & 1) * 64;
    f32x4_t accf[2][4] = {};
#pragma unroll
    for (int t = 0; t < 2; ++t) {
        const unsigned short* as = As + t * ASZ;
        const unsigned short* bs = Bs + t * BSZ;
#pragma unroll
        for (int kq = 0; kq < 2; ++kq) {
            bhalf8_t af[2], bf[4];
#pragma unroll
            for (int i = 0; i < 2; ++i)
                af[i] = *reinterpret_cast<const bhalf8_t*>(
                    &as[(wm + i * 16 + l16) * BKp + kq * 32 + quad * 8]);
#pragma unroll
            for (int j = 0; j < 4; ++j)
                bf[j] = *reinterpret_cast<const bhalf8_t*>(
                    &bs[(wn + j * 16 + l16) * BKp + kq * 32 + quad * 8]);
#pragma unroll
            for (int i = 0; i < 2; ++i)
#pragma unroll
                for (int j = 0; j < 4; ++j)
                    accf[i][j] = __builtin_amdgcn_mfma_f32_16x16x32_f16(
                        __builtin_bit_cast(half8_t, af[i]), __builtin_bit_cast(half8_t, bf[j]),
                        accf[i][j], 0, 0, 0);
        }
    }

    unsigned short* Cp = Cpart + (long)ks * kS * 512;
#pragma unroll
    for (int i = 0; i < 2; ++i)
#pragma unroll
        for (int j = 0; j < 4; ++j)
#pragma unroll
            for (int r = 0; r < 4; ++r) {
                int m = bm + wm + i * 16 + quad * 4 + r;
                int n = bn + wn + j * 16 + l16;
                Cp[(long)m * 512 + n] = f2h(accf[i][j][r]);
            }
}

// ------ flash partial: 8 waves share one (h,z) K/V slice staged in LDS ----------
// block = 512 thr = 8 q-blocks of 16 rows; grid 512 = 8 qbg x 8 h x 8 z.
// Halves the K/V staging redundancy vs the 4-wave version.
__global__ __launch_bounds__(512, 4)
void flash_part_k(const unsigned short* __restrict__ qb2, const unsigned short* __restrict__ kb2,
                  const unsigned short* __restrict__ vtb, const unsigned short* __restrict__ bmap,
                  unsigned short* __restrict__ po, float* __restrict__ pm, float* __restrict__ pl)
{
    constexpr int KP = 136;                 // padded row stride (16B-aligned rows)
    __shared__ __align__(16) unsigned short Klds[128 * KP];   // 34816 B; Ps later
    __shared__ __align__(16) unsigned short Vlds[64 * KP];    // 17408 B

    int tid = threadIdx.x;
    int w    = tid >> 6;                    // 8 waves
    int lane = tid & 63;
    int quad = lane >> 4, l16 = lane & 15;

    int wg  = blockIdx.x;                   // 512 = 8 XCD chunks x 64
    int lin = (wg & 7) * 64 + (wg >> 3);    // bijective (512 % 8 == 0)
    int qbg = lin & 7;
    int h   = (lin >> 3) & 7;
    int z   = lin >> 6;
    int qb  = qbg * 8 + w;
    int bm  = qb * 16;
    int k0  = z * 128;

    const unsigned short* Qh = qb2 + (long)h * 131072;
    const unsigned short* Kh = kb2 + (long)h * 131072;
    const unsigned short* Vh = vtb + (long)h * 65536;
    const unsigned short* Bm = bmap + (long)h * 1048576;

    // ---- cooperative stage: K (128 keys x 128), V (64 dims x 128 keys) ----
    {
        int kr = tid >> 2, kc = (tid & 3) * 32;
#pragma unroll
        for (int j = 0; j < 4; ++j)
            *reinterpret_cast<bhalf8_t*>(&Klds[kr * KP + kc + j * 8]) =
                *reinterpret_cast<const bhalf8_t*>(&Kh[(long)(k0 + kr) * 128 + kc + j * 8]);
        int vr = tid >> 3, vc = (tid & 7) * 16;
#pragma unroll
        for (int j = 0; j < 2; ++j)
            *reinterpret_cast<bhalf8_t*>(&Vlds[vr * KP + vc + j * 8]) =
                *reinterpret_cast<const bhalf8_t*>(&Vh[(long)vr * 1024 + k0 + vc + j * 8]);
    }

    // Q fragments (global, per-wave) + vectorized bias loads (permuted bmap)
    bhalf8_t aq[4];
#pragma unroll
    for (int kq = 0; kq < 4; ++kq)
        aq[kq] = *reinterpret_cast<const bhalf8_t*>(
            &Qh[(long)(bm + l16) * 128 + kq * 32 + quad * 8]);
    bhalf8_t bias8[4];
#pragma unroll
    for (int r = 0; r < 4; ++r) {
        int gm = bm + quad * 4 + r;
        bias8[r] = *reinterpret_cast<const bhalf8_t*>(
            &Bm[(long)gm * 1024 + z * 128 + l16 * 8]);
    }

    __syncthreads();                        // K/V staged

    f32x4_t sacc[8] = {};
#pragma unroll
    for (int kq = 0; kq < 4; ++kq) {
        bhalf8_t bk[8];
#pragma unroll
        for (int nb = 0; nb < 8; ++nb)
            bk[nb] = *reinterpret_cast<const bhalf8_t*>(
                &Klds[(nb * 16 + l16) * KP + kq * 32 + quad * 8]);
#pragma unroll
        for (int nb = 0; nb < 8; ++nb)
            sacc[nb] = __builtin_amdgcn_mfma_f32_16x16x32_f16(
                __builtin_bit_cast(half8_t, aq[kq]), __builtin_bit_cast(half8_t, bk[nb]),
                sacc[nb], 0, 0, 0);
    }

    float m_r[4] = {-3.0e38f, -3.0e38f, -3.0e38f, -3.0e38f};
#pragma unroll
    for (int nb = 0; nb < 8; ++nb)
#pragma unroll
        for (int r = 0; r < 4; ++r) {
            float bias = h2f((unsigned short)bias8[r][nb]);
            float s = fmaf(sacc[nb][r], 0.125f, bias);
            sacc[nb][r] = s;
            m_r[r] = fmaxf(m_r[r], s);
        }
#pragma unroll
    for (int r = 0; r < 4; ++r) {
        float m_ = m_r[r];
#pragma unroll
        for (int off = 1; off < 16; off <<= 1) m_ = fmaxf(m_, __shfl_xor(m_, off, 64));
        m_r[r] = m_;
    }

    __syncthreads();                        // all waves done reading Klds

    unsigned short* Ps = Klds + w * 16 * KP;   // per-wave 16 x KP (8 waves fill 128)
    float l_r[4];
#pragma unroll
    for (int r = 0; r < 4; ++r) {
        int row = quad * 4 + r;
        float mN = m_r[r];
        float s_ = 0.f;
#pragma unroll
        for (int nb = 0; nb < 8; ++nb) {
            float p = __expf(sacc[nb][r] - mN);
            Ps[row * KP + nb * 16 + l16] = f2h(p * 16384.f);
            s_ += p;
        }
#pragma unroll
        for (int off = 1; off < 16; off <<= 1) s_ += __shfl_xor(s_, off, 64);
        l_r[r] = s_;
    }

    long sbase = (((long)z * 8 + h) * 64 + qb) * 16;
    if (l16 == 0) {
#pragma unroll
        for (int r = 0; r < 4; ++r) {
            pm[sbase + quad * 4 + r] = m_r[r];
            pl[sbase + quad * 4 + r] = l_r[r];
        }
    }

    f32x4_t oacc[4] = {};
#pragma unroll
    for (int kq2 = 0; kq2 < 4; ++kq2) {
        bhalf8_t ap = *reinterpret_cast<const bhalf8_t*>(&Ps[l16 * KP + kq2 * 32 + quad * 8]);
#pragma unroll
        for (int j2 = 0; j2 < 4; ++j2) {
            bhalf8_t bv = *reinterpret_cast<const bhalf8_t*>(
                &Vlds[(j2 * 16 + l16) * KP + kq2 * 32 + quad * 8]);
            oacc[j2] = __builtin_amdgcn_mfma_f32_16x16x32_f16(
                __builtin_bit_cast(half8_t, ap), __builtin_bit_cast(half8_t, bv),
                oacc[j2], 0, 0, 0);
        }
    }

    unsigned short* pob = po + sbase * 64;
#pragma unroll
    for (int j2 = 0; j2 < 4; ++j2)
#pragma unroll
        for (int r = 0; r < 4; ++r)
            pob[(quad * 4 + r) * 64 + j2 * 16 + l16] =
                f2h(oacc[j2][r] * (1.f / 16777216.f));
}

// ---------------- fused: f16 split-K reduce + bias + residual + LN + f16 xb -----
__global__ __launch_bounds__(256)
void add_ln_fused_k(const unsigned short* __restrict__ part, float* __restrict__ x,
                    const float* __restrict__ bias,
                    const float* __restrict__ g, const float* __restrict__ b,
                    unsigned short* __restrict__ xb, int splitk)
{
    __shared__ float sm[4];
    int row = blockIdx.x, t = threadIdx.x;
    const long MN = (long)kS * kD;
    float* xr = x + (long)row * kD;
    float s0 = 0.f, s1 = 0.f;
    const unsigned short* pr = part + (long)row * kD;
    for (int sl = 0; sl < splitk; ++sl) {
        s0 += h2f(pr[(long)sl * MN + t]);
        s1 += h2f(pr[(long)sl * MN + t + 256]);
    }
    s0 += bias[t] + xr[t];
    s1 += bias[t + 256] + xr[t + 256];
    float sum = wave_sum(s0 + s1);
    if ((t & 63) == 0) sm[t >> 6] = sum;
    __syncthreads();
    sum = sm[0] + sm[1] + sm[2] + sm[3];
    float mu = sum * (1.f / kD);
    float d0 = s0 - mu, d1 = s1 - mu;
    __syncthreads();
    float vs = wave_sum(d0 * d0 + d1 * d1);
    if ((t & 63) == 0) sm[t >> 6] = vs;
    __syncthreads();
    vs = sm[0] + sm[1] + sm[2] + sm[3];
    float rs = rsqrtf(vs * (1.f / kD) + 1e-5f);
    float o0 = fmaf(d0 * rs, g[t], b[t]);
    float o1 = fmaf(d1 * rs, g[t + 256], b[t + 256]);
    xr[t]       = o0;
    xr[t + 256] = o1;
    unsigned short* xrow = xb + (long)row * 512;
    xrow[t]       = f2h(o0);
    xrow[t + 256] = f2h(o1);
}

// ----- pool + classifier head, 3-phase: pool | spin-barrier | parallel h1 | c2 ---
__global__ __launch_bounds__(256)
void pool_head_k(const float* __restrict__ x, float* __restrict__ partial,
                 float* __restrict__ h1g, unsigned int* __restrict__ cnt2,
                 const float* __restrict__ c1w, const float* __restrict__ c1b,
                 const float* __restrict__ c2w, const float* __restrict__ c2b,
                 float* __restrict__ out)
{
    __shared__ float pooled[kD];
    __shared__ int flag;
    int t = threadIdx.x;
    int bid = blockIdx.x;
    int cb = bid & 1, rb = bid >> 1;   // 16 blocks: 2 col x 8 row
    int col = cb * 256 + t;
    float s = 0.f;
    for (int r = rb * 128; r < rb * 128 + 128; ++r) s += x[(long)r * kD + col];
    partial[rb * kD + col] = s;

    // ---- spin barrier across the 16 blocks (all co-resident) ----
    __threadfence();
    if (t == 0) {
        atomicAdd(&cnt2[0], 1u);
        while (atomicAdd(&cnt2[0], 0u) < 16u) {}
    }
    __syncthreads();
    __threadfence();

    // ---- full pooled vector (all blocks, redundant but tiny) ----
    {
        float p0 = 0.f, p1 = 0.f;
#pragma unroll
        for (int r = 0; r < 8; ++r) {
            p0 += partial[r * kD + t];
            p1 += partial[r * kD + t + 256];
        }
        pooled[t]       = p0 * (1.0f / kS);
        pooled[t + 256] = p1 * (1.0f / kS);
    }
    __syncthreads();

    // ---- h1 slice: block bid -> cols [bid*16, bid*16+16), 16 threads/col ----
    {
        int c = bid * 16 + (t >> 4);
        int sub = t & 15;
        float a = 0.f;
        for (int f = sub; f < kD; f += 16)
            a = fmaf(pooled[f], c1w[(long)f * 256 + c], a);
#pragma unroll
        for (int o = 1; o < 16; o <<= 1) a += __shfl_xor(a, o, 64);
        if (sub == 0) h1g[c] = fmaxf(a + c1b[c], 0.f);
    }

    // ---- last-arriver does c2 (tiny, parallel over 160 threads) ----
    __threadfence();
    if (t == 0) flag = (atomicAdd(&cnt2[1], 1u) == 15u);
    __syncthreads();
    if (!flag) return;
    __threadfence();

    if (t < 160) {
        int c = t >> 4, sub = t & 15;
        float a = 0.f;
        for (int f = sub; f < 256; f += 16)
            a = fmaf(h1g[f], c2w[(long)f * 10 + c], a);
#pragma unroll
        for (int o = 1; o < 16; o <<= 1) a += __shfl_xor(a, o, 64);
        if (sub == 0) out[c] = a + c2b[c];
    }
}

// ---------------- launch ----------------
extern "C" void kernel_launch(void* const* d_in, const int* in_sizes, int n_in,
                              void* d_out, int out_size, void* d_ws, size_t ws_size,
                              hipStream_t stream)
{
    (void)in_sizes; (void)n_in; (void)out_size; (void)ws_size;
    const float* features = (const float*)d_in[0];
    const float* positions= (const float*)d_in[1];
    const float* fb       = (const float*)d_in[2];
    const float* in_w     = (const float*)d_in[3];
    const float* in_b     = (const float*)d_in[4];
    const float* qw  = (const float*)d_in[5];
    const float* qb  = (const float*)d_in[6];
    const float* kw  = (const float*)d_in[7];
    const float* kb  = (const float*)d_in[8];
    const float* vw  = (const float*)d_in[9];
    const float* vb  = (const float*)d_in[10];
    const float* ow  = (const float*)d_in[11];
    const float* ob  = (const float*)d_in[12];
    const float* db1w= (const float*)d_in[13];
    const float* db1b= (const float*)d_in[14];
    const float* db2w= (const float*)d_in[15];
    const float* db2b= (const float*)d_in[16];
    const float* n1g = (const float*)d_in[17];
    const float* n1b = (const float*)d_in[18];
    const float* n2g = (const float*)d_in[19];
    const float* n2b = (const float*)d_in[20];
    const float* f1w = (const float*)d_in[21];
    const float* f1b = (const float*)d_in[22];
    const float* f2w = (const float*)d_in[23];
    const float* f2b = (const float*)d_in[24];
    const float* c1w = (const float*)d_in[25];
    const float* c1b = (const float*)d_in[26];
    const float* c2w = (const float*)d_in[27];
    const float* c2b = (const float*)d_in[28];

    float* ws = (float*)d_ws;
    const long SD = (long)kS * kD;            // 524288
    float* x      = ws;
    float* part_f = ws + 5 * SD;              // scratch region (reused), 12*SD floats
    float* bpw    = ws + 17 * SD;
    float* Atab   = bpw + 256;
    float* Btab   = Atab + 2080;
    float* partial= Btab + 2080;

    // scratch carve (floats from part_f):
    unsigned short* part16 = (unsigned short*)part_f;
    unsigned short* po     = (unsigned short*)part_f;
    float* pmv = part_f + 2162688;
    float* plv = pmv + 65536;
    unsigned int* cnt2 = (unsigned int*)(plv + 65536);
    float* h1g = (float*)(cnt2 + 16);
    unsigned short* part16b = (unsigned short*)(part_f + 2294048);

    unsigned short* ub = (unsigned short*)(ws + 17 * SD + 8512);
    unsigned short* xb   = ub;                       // 1024*512 (f16)
    unsigned short* qb2  = ub   + 1048576;           // 8*1024*128 (2-seg)
    unsigned short* kb2  = qb2  + 1048576;
    unsigned short* vtb  = kb2  + 1048576;           // 512*1024 (f16)
    unsigned short* hb   = vtb  + 524288;            // 1024*2048
    unsigned short* qwb  = hb   + 2097152;           // 2 x 512*512
    unsigned short* kwb  = qwb  + 524288;
    unsigned short* vwb  = kwb  + 524288;
    unsigned short* owb  = vwb  + 524288;
    unsigned short* f1wb = owb  + 524288;            // 2 x 2048*512
    unsigned short* f2wb = f1wb + 2097152;           // 2 x 512*2048
    unsigned short* bmap = f2wb + 2097152;           // 8*1024*1024 f16 (permuted)

    // single merged preamble (dist removed; biasmap computes it on the fly)
    prep_k<<<6530, 256, 0, stream>>>(features, positions, fb, in_w, in_b, x, xb,
                                     qw, kw, vw, ow, qwb, kwb, vwb, owb,
                                     f1w, f1wb, f2w, f2wb,
                                     db1w, db1b, db2w, db2b, bpw, Atab, Btab);

    for (int l = 0; l < 2; ++l) {
        // QKV GEMM (192 blocks) + biasmap (1024 blocks backfill) + cnt2 zeroing
        qkv_bias_k<<<1216, 256, 0, stream>>>(
            xb, qwb + l * 262144, kwb + l * 262144, vwb + l * 262144,
            qb + l * kD, kb + l * kD, vb + l * kD, qb2, kb2, vtb,
            positions, bpw + l * 128, Atab + l * 1040, Btab + l * 1040, bmap, cnt2);

        // fused attention: 8-wave blocks, K/V in LDS (2x less staging redundancy)
        flash_part_k<<<512, 512, 0, stream>>>(
            qb2, kb2, vtb, bmap, po, pmv, plv);

        // O-proj with flash-merge fused into A-staging -> part16b
        bgemm_oproj_k<<<dim3(16, 4, 4), 256, 0, stream>>>(
            po, pmv, plv, owb + l * 262144, part16b);
        add_ln_fused_k<<<kS, 256, 0, stream>>>(
            part16b, x, ob + l * kD, n1g + l * kD, n1b + l * kD, xb, 4);

        // FFN1: no split-K (256 blocks), bias+relu -> hb f16
        bgemm_ffn1_k<<<dim3(16, 16), 256, 0, stream>>>(
            xb, f1wb + l * 1048576, f1b + l * kDFF, hb);

        // FFN2: K=2048, split-K x4 (256 blocks); reduce fused into add_ln
        bgemm_k<512><<<dim3(16, 4, 4), 256, 0, stream>>>(
            hb, f2wb + l * 1048576, 512, 2048, 2048, part16);
        add_ln_fused_k<<<kS, 256, 0, stream>>>(
            part16, x, f2b + l * kD, n2g + l * kD, n2b + l * kD, xb, 4);
    }

    // pool + parallel classifier head (16-block spin barrier, fences tiny at 16)
    pool_head_k<<<16, 256, 0, stream>>>(x, partial, h1g, cnt2,
                                        c1w, c1b, c2w, c2b, (float*)d_out);
}

// Round 12
// 267.610 us; speedup vs baseline: 1.0458x; 1.0458x over previous
//
#include <hip/hip_runtime.h>

namespace {
constexpr int kS   = 1024;
constexpr int kD   = 512;
constexpr int kDFF = 2048;
constexpr int kNF  = 85;   // D//6
}

typedef __attribute__((ext_vector_type(8))) short bhalf8_t;    // 8x16-bit in 4 VGPRs
typedef _Float16 half8_t __attribute__((ext_vector_type(8)));
typedef __attribute__((ext_vector_type(4))) float f32x4_t;

// ---------------- helpers ----------------
__device__ __forceinline__ float wave_sum(float v) {
#pragma unroll
    for (int o = 1; o < 64; o <<= 1) v += __shfl_xor(v, o, 64);
    return v;
}
__device__ __forceinline__ unsigned short f2h(float f) {    // RNE fp32->fp16
    _Float16 h = (_Float16)f;
    return __builtin_bit_cast(unsigned short, h);
}
__device__ __forceinline__ float h2f(unsigned short u) {
    return (float)__builtin_bit_cast(_Float16, u);
}

// ---- 32x32 f32->f16 transpose tile helper ----
__device__ __forceinline__ void tr_tile32(const float* __restrict__ in,
                                          unsigned short* __restrict__ out,
                                          int N, int K, int k0, int n0, int t,
                                          float* tile /*32*33*/)
{
    int r = t >> 3, c4 = (t & 7) * 4;
    float4 v = *reinterpret_cast<const float4*>(&in[(long)(k0 + r) * N + n0 + c4]);
    tile[r * 33 + c4] = v.x; tile[r * 33 + c4 + 1] = v.y;
    tile[r * 33 + c4 + 2] = v.z; tile[r * 33 + c4 + 3] = v.w;
    __syncthreads();
    int nr = t >> 3, kq = (t & 7) * 4;
    unsigned short h[4];
#pragma unroll
    for (int j = 0; j < 4; ++j) h[j] = f2h(tile[(kq + j) * 33 + nr]);
    *reinterpret_cast<ushort4*>(&out[(long)(n0 + nr) * K + k0 + kq]) =
        make_ushort4(h[0], h[1], h[2], h[3]);
}

// ======= single preamble: input_pe(4-row) | dist | transposes | pwl_tab+sort =====
__global__ __launch_bounds__(256)
void prep_k(const float* __restrict__ feat, const float* __restrict__ pos,
            const float* __restrict__ fb, const float* __restrict__ in_w,
            const float* __restrict__ in_b, float* __restrict__ x,
            unsigned short* __restrict__ xb, float* __restrict__ dist,
            const float* __restrict__ qw, const float* __restrict__ kw,
            const float* __restrict__ vw, const float* __restrict__ ow,
            unsigned short* __restrict__ qwb, unsigned short* __restrict__ kwb,
            unsigned short* __restrict__ vwb, unsigned short* __restrict__ owb,
            const float* __restrict__ f1w, unsigned short* __restrict__ f1wb,
            const float* __restrict__ f2w, unsigned short* __restrict__ f2wb,
            const float* __restrict__ a_, const float* __restrict__ b_,
            const float* __restrict__ w2, const float* __restrict__ b2,
            float* __restrict__ bp_out, float* __restrict__ Atab,
            float* __restrict__ Btab)
{
    __shared__ float smem[1056];
    int bid = blockIdx.x;
    int t = threadIdx.x;
    if (bid < 256) {
        // ---- input projection + PE, 4 rows/block ----
        int s0 = bid * 4;
        smem[t] = feat[s0 * 64 + t];           // 4 rows x 64 feat
        __syncthreads();
        float b0 = in_b[t], b1 = in_b[t + 256];
        float a0[4] = {b0, b0, b0, b0}, a1[4] = {b1, b1, b1, b1};
#pragma unroll 4
        for (int c = 0; c < 64; ++c) {
            float w0 = in_w[c * kD + t], w1 = in_w[c * kD + 256 + t];
#pragma unroll
            for (int r = 0; r < 4; ++r) {
                a0[r] = fmaf(smem[r * 64 + c], w0, a0[r]);
                a1[r] = fmaf(smem[r * 64 + c], w1, a1[r]);
            }
        }
#pragma unroll
        for (int r = 0; r < 4; ++r) {
            int s = s0 + r;
            float pe0 = 0.f, pe1 = 0.f;
            int d = t;
            if (d < 6 * kNF) {
                int seg = d / kNF, idx = d - seg * kNF;
                float cs = pos[s * 3 + (seg >> 1)] * fb[idx];
                pe0 = (seg & 1) ? cosf(cs) : sinf(cs);
            }
            d = t + 256;
            if (d < 6 * kNF) {
                int seg = d / kNF, idx = d - seg * kNF;
                float cs = pos[s * 3 + (seg >> 1)] * fb[idx];
                pe1 = (seg & 1) ? cosf(cs) : sinf(cs);
            }
            float o0 = a0[r] + pe0, o1 = a1[r] + pe1;
            x[s * kD + t]        = o0;
            x[s * kD + 256 + t]  = o1;
            xb[s * kD + t]       = f2h(o0);
            xb[s * kD + 256 + t] = f2h(o1);
        }
    } else if (bid < 1280) {
        // ---- pairwise distance ----
        int i = bid - 256;
        float px = pos[i * 3], py = pos[i * 3 + 1], pz = pos[i * 3 + 2];
        for (int j = t; j < kS; j += 256) {
            float dx = px - pos[j * 3], dy = py - pos[j * 3 + 1], dz = pz - pos[j * 3 + 2];
            float sq = dx * dx + dy * dy + dz * dz;
            dist[(long)i * kS + j] = sq > 0.f ? sqrtf(sq) : 0.f;
        }
    } else if (bid < 7424) {
        // ---- weight transposes ----
        int idx = bid - 1280;
        if (idx < 2048) {
            int zz = idx >> 8, rem = idx & 255;
            int mat = zz >> 1, layer = zz & 1;
            const float* in = (mat == 0) ? qw : (mat == 1) ? kw : (mat == 2) ? vw : ow;
            unsigned short* out = (mat == 0) ? qwb : (mat == 1) ? kwb : (mat == 2) ? vwb : owb;
            tr_tile32(in + (long)layer * 262144, out + (long)layer * 262144,
                      512, 512, (rem & 15) * 32, (rem >> 4) * 32, t, smem);
        } else if (idx < 4096) {
            int l = idx - 2048;
            int z = l >> 10;
            tr_tile32(f1w + (long)z * 1048576, f1wb + (long)z * 1048576,
                      2048, 512, (l & 15) * 32, ((l >> 4) & 63) * 32, t, smem);
        } else {
            int l = idx - 4096;
            int z = l >> 10;
            tr_tile32(f2w + (long)z * 1048576, f2wb + (long)z * 1048576,
                      512, 2048, (l & 63) * 32, ((l >> 6) & 15) * 32, t, smem);
        }
    } else {
        // ---- pwl_tab with local breakpoint sort: 129 segs x 2 layers ----
        int l = bid - 7424;
        int seg = l % 129, ly = l / 129;
        const float* ap = a_ + ly * 128;
        const float* bpp = b_ + ly * 128;
        const float* w2p = w2 + ly * 1024;
        const float* b2p = b2 + ly * 8;
        float* At = Atab + ly * 1040;
        float* Bt = Btab + ly * 1040;

        if (t < 128) {
            float a = ap[t], b = bpp[t];
            smem[t] = (a != 0.f) ? (-b / a) : 3.0e38f;
        }
        __syncthreads();
        for (int ksz = 2; ksz <= 128; ksz <<= 1) {
            for (int j = ksz >> 1; j > 0; j >>= 1) {
                if (t < 128) {
                    int ixj = t ^ j;
                    if (ixj > t) {
                        bool up = ((t & ksz) == 0);
                        float x0 = smem[t], x1 = smem[ixj];
                        if ((x0 > x1) == up) { smem[t] = x1; smem[ixj] = x0; }
                    }
                }
                __syncthreads();
            }
        }
        float m;
        if (seg == 0)        m = smem[0] - 1.0f;
        else if (seg == 128) m = smem[127] + 1.0f;
        else                 m = 0.5f * (smem[seg - 1] + smem[seg]);
        if (seg == 0 && t < 128) bp_out[ly * 128 + t] = smem[t];  // for biasmap
        __syncthreads();                       // all reads of keys done

        int h = t & 7, cg = t >> 3;
        float A = 0.f, B = 0.f;
#pragma unroll
        for (int j = 0; j < 4; ++j) {
            int c = cg * 4 + j;
            float a = ap[c], b = bpp[c];
            if (fmaf(a, m, b) > 0.f) {
                float w = w2p[c * 8 + h];
                A = fmaf(a, w, A);
                B = fmaf(b, w, B);
            }
        }
#pragma unroll
        for (int off = 8; off < 64; off <<= 1) {
            A += __shfl_xor(A, off, 64);
            B += __shfl_xor(B, off, 64);
        }
        int w = t >> 6, lane = t & 63;
        if (lane < 8) { smem[w * 8 + lane] = A; smem[32 + w * 8 + lane] = B; }
        __syncthreads();
        if (t < 8) {
            float At_ = smem[t] + smem[8 + t] + smem[16 + t] + smem[24 + t];
            float Bt_ = smem[32 + t] + smem[40 + t] + smem[48 + t] + smem[56 + t];
            At[seg * 8 + t] = At_;
            Bt[seg * 8 + t] = Bt_ + b2p[t];
        }
    }
}

// ====== GEMM core v3: global_load_lds + XOR swizzle + COUNTED vmcnt (T4) =========
constexpr int ASZ2 = 64 * 64;     // shorts per A buffer (8KB)
constexpr int BSZ2 = 128 * 64;    // shorts per B buffer (16KB)

// old-stride constants kept for the O-proj custom path + V-transpose region
constexpr int BKp = 72;
constexpr int ASZ = 64 * BKp;
constexpr int BSZ = 128 * BKp;

__device__ __forceinline__ void gload16(const unsigned short* g, unsigned short* l) {
    __builtin_amdgcn_global_load_lds(
        (const __attribute__((address_space(1))) unsigned int*)g,
        (__attribute__((address_space(3))) unsigned int*)l, 16, 0, 0);
}

template<int K>
__device__ __forceinline__ void gemm_core(
    const unsigned short* __restrict__ Ap, const unsigned short* __restrict__ Bp,
    int lda, int ldb, int bm, int bn, int tid,
    unsigned short* __restrict__ As, unsigned short* __restrict__ Bs,
    f32x4_t acc[2][4])
{
    int w = tid >> 6, lane = tid & 63, quad = lane >> 4, l16 = lane & 15;
    int wm = (w >> 1) * 32, wn = (w & 1) * 64;
    int lr = lane >> 3;              // row within 8-row group (== row&7)
    int sw = (lane & 7) ^ lr;        // logical col16 fetched into physical slot lane&7

    const unsigned short* pa  = Ap + (long)(bm + w * 16 + lr) * lda + sw * 8;
    const unsigned short* pa2 = pa + (long)8 * lda;
    const unsigned short* pb  = Bp + (long)(bn + w * 32 + lr) * ldb + sw * 8;

    auto stage = [&](int t) {
        int buf = t % 3;
        unsigned short* as = As + buf * ASZ2 + w * 16 * 64;
        unsigned short* bs = Bs + buf * BSZ2 + w * 32 * 64;
        int k0 = t * 64;
        gload16(pa + k0, as);
        gload16(pa2 + k0, as + 8 * 64);
#pragma unroll
        for (int j = 0; j < 4; ++j)
            gload16(pb + (long)(j * 8) * ldb + k0, bs + j * 8 * 64);
    };

    constexpr int NT = K / 64;
    stage(0);
    if (NT > 1) stage(1);
    int r7 = l16 & 7;
#pragma unroll
    for (int t = 0; t < NT; ++t) {
        // wait until stage(t) landed; stage(t+1)'s 6 loads may stay outstanding
        if (t + 1 < NT) asm volatile("s_waitcnt vmcnt(6)" ::: "memory");
        else            asm volatile("s_waitcnt vmcnt(0)" ::: "memory");
        __builtin_amdgcn_s_barrier();
        __builtin_amdgcn_sched_barrier(0);
        if (t + 2 < NT) stage(t + 2);          // into buf freed at step t-1
        const unsigned short* as = As + (t % 3) * ASZ2;
        const unsigned short* bs = Bs + (t % 3) * BSZ2;
#pragma unroll
        for (int kq = 0; kq < 2; ++kq) {
            int slot = ((kq * 4 + quad) ^ r7) * 8;
            bhalf8_t af[2], bf[4];
#pragma unroll
            for (int i = 0; i < 2; ++i)
                af[i] = *reinterpret_cast<const bhalf8_t*>(
                    &as[(wm + i * 16 + l16) * 64 + slot]);
#pragma unroll
            for (int j = 0; j < 4; ++j)
                bf[j] = *reinterpret_cast<const bhalf8_t*>(
                    &bs[(wn + j * 16 + l16) * 64 + slot]);
#pragma unroll
            for (int i = 0; i < 2; ++i)
#pragma unroll
                for (int j = 0; j < 4; ++j)
                    acc[i][j] = __builtin_amdgcn_mfma_f32_16x16x32_f16(
                        __builtin_bit_cast(half8_t, af[i]), __builtin_bit_cast(half8_t, bf[j]),
                        acc[i][j], 0, 0, 0);
        }
    }
}

// ========== merged: QKV GEMM (192 blocks, first) | biasmap (1024 blocks) =========
// bmap layout is PERMUTED for vectorized flash reads:
//   element (gm, gn) stored at [h][gm][ (gn>>7)*128 + (gn&15)*8 + ((gn>>4)&7) ]
// biasmap block = one dist row (gm); values staged in LDS (padded per-z stripe),
// then written as coalesced 16B stores (was: 32 scattered 2B stores/thread).
__global__ __launch_bounds__(256, 2)
void qkv_bias_k(const unsigned short* __restrict__ xb,
                const unsigned short* __restrict__ qwb, const unsigned short* __restrict__ kwb,
                const unsigned short* __restrict__ vwb,
                const float* __restrict__ qbias, const float* __restrict__ kbias,
                const float* __restrict__ vbias,
                unsigned short* __restrict__ qb2, unsigned short* __restrict__ kb2,
                unsigned short* __restrict__ vtb,
                const float* __restrict__ dist, const float* __restrict__ bp,
                const float* __restrict__ Atab, const float* __restrict__ Btab,
                unsigned short* __restrict__ bmap, unsigned int* __restrict__ cnt)
{
    __shared__ __align__(16) unsigned short smem[3 * ASZ2 + 3 * BSZ2];  // 73728 B
    int bid = blockIdx.x;
    int tid = threadIdx.x;
    if (bid < 192) {
        int z = bid >> 6, rem = bid & 63;
        int bm = (rem & 15) * 64, bn = (rem >> 4) * 128;
        const unsigned short* Bp = (z == 1) ? kwb : (z == 2) ? vwb : qwb;
        const float* bias = (z == 1) ? kbias : (z == 2) ? vbias : qbias;
        f32x4_t acc[2][4] = {};
        gemm_core<512>(xb, Bp, 512, 512, bm, bn, tid, smem, smem + 3 * ASZ2, acc);

        int w = tid >> 6, lane = tid & 63, quad = lane >> 4, l16 = lane & 15;
        int wm = (w >> 1) * 32, wn = (w & 1) * 64;
        if (z == 2) {
            // fused V transpose: write vtb[h][d][s] = f16((v+bias)*1024)
            __syncthreads();                         // all waves done with LDS
            unsigned short* T = smem;                // 128 x 72 region
#pragma unroll
            for (int j = 0; j < 4; ++j) {
                int ln = wn + j * 16 + l16;
                float bv = bias[bn + ln];
#pragma unroll
                for (int i = 0; i < 2; ++i)
#pragma unroll
                    for (int r = 0; r < 4; ++r)
                        T[ln * BKp + wm + i * 16 + quad * 4 + r] =
                            f2h((acc[i][j][r] + bv) * 1024.f);
            }
            __syncthreads();
            int nr = tid >> 1, mc = (tid & 1) * 32;
            int gn = bn + nr;
            unsigned short* dst = vtb + (long)(gn >> 6) * 65536
                                + (long)(gn & 63) * 1024 + bm + mc;
#pragma unroll
            for (int jj = 0; jj < 4; ++jj)
                *reinterpret_cast<bhalf8_t*>(dst + jj * 8) =
                    *reinterpret_cast<const bhalf8_t*>(&T[nr * BKp + mc + jj * 8]);
        } else {
#pragma unroll
            for (int j = 0; j < 4; ++j) {
                int n = bn + wn + j * 16 + l16;
                float bv = bias[n];
                unsigned short* dst = ((z == 1) ? kb2 : qb2)
                    + (long)(n >> 6) * 131072 + (n & 63);
#pragma unroll
                for (int i = 0; i < 2; ++i)
#pragma unroll
                    for (int r = 0; r < 4; ++r) {
                        int m = bm + wm + i * 16 + quad * 4 + r;
                        float s = acc[i][j][r] + bv;
                        unsigned short hi = f2h(s);
                        dst[(long)m * 128]      = hi;
                        dst[(long)m * 128 + 64] = (z == 0) ? f2h(s - h2f(hi)) : hi;
                    }
            }
        }
    } else {
        // zero the pool/head counters
        if (bid == 192 && tid < 8) cnt[tid] = 0;
        // ---- biasmap: PWL eval of one dist row -> permuted f16 map, LDS-staged ----
        float* fs = reinterpret_cast<float*>(smem);
        float* bps = fs;            // 128 floats
        float* Ah  = fs + 128;      // 1032
        float* Bh  = fs + 1160;     // 1032  (total 2192 floats = 4384 shorts)
        // perm LDS: 8 heads x (8 z x 136pad) shorts = 8704 shorts, 16B-aligned
        unsigned short* perm = smem + 4384;
        int t = tid;
        if (t < 128) bps[t] = bp[t];
        for (int i = t; i < 1032; i += 256) { Ah[i] = Atab[i]; Bh[i] = Btab[i]; }
        __syncthreads();

        long gm = bid - 192;                    // one dist row per block
        int gn0 = t * 4;
        float4 d4 = *reinterpret_cast<const float4*>(dist + gm * 1024 + gn0);
        float dv[4] = {d4.x, d4.y, d4.z, d4.w};
        int seg[4];
#pragma unroll
        for (int j = 0; j < 4; ++j) {
            float tv = dv[j];
            int lo = 0, hi = 128;
            while (lo < hi) { int mid = (lo + hi) >> 1; if (bps[mid] < tv) lo = mid + 1; else hi = mid; }
            seg[j] = lo;
        }
        int zz = gn0 >> 7, nb = (gn0 >> 4) & 7, c4 = gn0 & 15;
        int pb0 = zz * 136 + nb;
#pragma unroll
        for (int h = 0; h < 8; ++h) {
            unsigned short* ph = perm + h * 1088 + pb0;
#pragma unroll
            for (int j = 0; j < 4; ++j)
                ph[(c4 + j) * 8] =
                    f2h(fmaf(Ah[seg[j] * 8 + h], dv[j], Bh[seg[j] * 8 + h]));
        }
        __syncthreads();
        // coalesced write-out: 8192 shorts = 256 thr x 4 x bhalf8
#pragma unroll
        for (int it = 0; it < 4; ++it) {
            int idx = it * 2048 + t * 8;
            int h   = idx >> 10;
            int off = idx & 1023;
            int z2  = off >> 7, r = off & 127;
            *reinterpret_cast<bhalf8_t*>(bmap + (long)h * 1048576 + gm * 1024 + off) =
                *reinterpret_cast<const bhalf8_t*>(&perm[h * 1088 + z2 * 136 + r]);
        }
    }
}

// ---------------- FFN1 GEMM, fused bias + relu -> hb f16 ----------------
__global__ __launch_bounds__(256, 2)
void bgemm_ffn1_k(const unsigned short* __restrict__ A,
                  const unsigned short* __restrict__ B,
                  const float* __restrict__ bias,
                  unsigned short* __restrict__ hb)
{
    __shared__ __align__(16) unsigned short smem[3 * ASZ2 + 3 * BSZ2];
    int tid = threadIdx.x;
    int bm = blockIdx.x * 64, bn = blockIdx.y * 128;
    f32x4_t acc[2][4] = {};
    gemm_core<512>(A, B, 512, 512, bm, bn, tid, smem, smem + 3 * ASZ2, acc);

    int w = tid >> 6, lane = tid & 63, quad = lane >> 4, l16 = lane & 15;
    int wm = (w >> 1) * 32, wn = (w & 1) * 64;
#pragma unroll
    for (int j = 0; j < 4; ++j) {
        int n = bn + wn + j * 16 + l16;
        float bv = bias[n];
#pragma unroll
        for (int i = 0; i < 2; ++i)
#pragma unroll
            for (int r = 0; r < 4; ++r) {
                int m = bm + wm + i * 16 + quad * 4 + r;
                hb[(long)m * kDFF + n] = f2h(fmaxf(acc[i][j][r] + bv, 0.f));
            }
    }
}

// -------- split-K GEMM -> f16 partials (FFN2 K=512/split) ----
template<int K>
__global__ __launch_bounds__(256, 2)
void bgemm_k(const unsigned short* __restrict__ A, const unsigned short* __restrict__ B,
             int N, int lda, int ldb, unsigned short* __restrict__ Cpart)
{
    __shared__ __align__(16) unsigned short smem[3 * ASZ2 + 3 * BSZ2];
    int tid = threadIdx.x;
    int ks = blockIdx.z;
    const unsigned short* Ap = A + (long)ks * K;
    const unsigned short* Bp = B + (long)ks * K;
    int bm = blockIdx.x * 64, bn = blockIdx.y * 128;
    f32x4_t acc[2][4] = {};
    gemm_core<K>(Ap, Bp, lda, ldb, bm, bn, tid, smem, smem + 3 * ASZ2, acc);

    int w = tid >> 6, lane = tid & 63, quad = lane >> 4, l16 = lane & 15;
    int wm = (w >> 1) * 32, wn = (w & 1) * 64;
    unsigned short* Cp = Cpart + (long)ks * kS * N;
#pragma unroll
    for (int i = 0; i < 2; ++i)
#pragma unroll
        for (int j = 0; j < 4; ++j)
#pragma unroll
            for (int r = 0; r < 4; ++r) {
                int m = bm + wm + i * 16 + quad * 4 + r;
                int n = bn + wn + j * 16 + l16;
                Cp[(long)m * N + n] = f2h(acc[i][j][r]);
            }
}

// ------- O-proj GEMM with flash-merge fused into A-staging (BK=64 = head_dim) ----
__global__ __launch_bounds__(256, 2)
void bgemm_oproj_k(const unsigned short* __restrict__ po,
                   const float* __restrict__ pm, const float* __restrict__ pl,
                   const unsigned short* __restrict__ Bw,
                   unsigned short* __restrict__ Cpart)
{
    __shared__ __align__(16) unsigned short As[2 * ASZ];
    __shared__ __align__(16) unsigned short Bs[2 * BSZ];
    __shared__ float wz_s[2][64][9];
    __shared__ float inv_s[2][64];

    int tid = threadIdx.x;
    int ks = blockIdx.z;
    int bm = blockIdx.x * 64, bn = blockIdx.y * 128;
    int h0 = ks * 2;

    // B for both K-steps: load + stage (no barrier needed yet)
    int br = tid >> 1, bc = (tid & 1) * 32;
    {
        const unsigned short* pb = Bw + (long)(bn + br) * 512 + ks * 128 + bc;
#pragma unroll
        for (int t = 0; t < 2; ++t) {
            bhalf8_t v0 = *reinterpret_cast<const bhalf8_t*>(pb + t * 64);
            bhalf8_t v1 = *reinterpret_cast<const bhalf8_t*>(pb + t * 64 + 8);
            bhalf8_t v2 = *reinterpret_cast<const bhalf8_t*>(pb + t * 64 + 16);
            bhalf8_t v3 = *reinterpret_cast<const bhalf8_t*>(pb + t * 64 + 24);
            unsigned short* bs = Bs + t * BSZ;
            *reinterpret_cast<bhalf8_t*>(&bs[br * BKp + bc])      = v0;
            *reinterpret_cast<bhalf8_t*>(&bs[br * BKp + bc + 8])  = v1;
            *reinterpret_cast<bhalf8_t*>(&bs[br * BKp + bc + 16]) = v2;
            *reinterpret_cast<bhalf8_t*>(&bs[br * BKp + bc + 24]) = v3;
        }
    }

    // softmax-merge weights for (step, row): tid<128 -> (t = tid>>6, r = tid&63)
    if (tid < 128) {
        int t = tid >> 6, r = tid & 63;
        long sidx = (long)(h0 + t) * 1024 + bm + r;
        float m[8], M = -3.0e38f;
#pragma unroll
        for (int z = 0; z < 8; ++z) { m[z] = pm[z * 8192 + sidx]; M = fmaxf(M, m[z]); }
        float lt = 0.f;
#pragma unroll
        for (int z = 0; z < 8; ++z) {
            float w = __expf(m[z] - M);
            wz_s[t][r][z] = w;
            lt = fmaf(pl[z * 8192 + sidx], w, lt);
        }
        inv_s[t][r] = 1.f / lt;
    }
    __syncthreads();                              // wz_s/inv_s visible

    // A merge-stage both steps: coalesced po reads (4 threads = one 128B row)
    int ar = tid >> 2, ac = (tid & 3) * 16;
#pragma unroll
    for (int t = 0; t < 2; ++t) {
        float inv = inv_s[t][ar];
        const unsigned short* p = po + ((long)(h0 + t) * 1024 + bm + ar) * 64 + ac;
        float acc[16] = {};
#pragma unroll
        for (int z = 0; z < 8; ++z) {
            float w = wz_s[t][ar][z];
            bhalf8_t v0 = *reinterpret_cast<const bhalf8_t*>(p + (long)z * 524288);
            bhalf8_t v1 = *reinterpret_cast<const bhalf8_t*>(p + (long)z * 524288 + 8);
#pragma unroll
            for (int j = 0; j < 8; ++j) {
                acc[j]     = fmaf(h2f((unsigned short)v0[j]), w, acc[j]);
                acc[8 + j] = fmaf(h2f((unsigned short)v1[j]), w, acc[8 + j]);
            }
        }
        unsigned short* as = As + t * ASZ;
#pragma unroll
        for (int j = 0; j < 16; ++j)
            as[ar * BKp + ac + j] = f2h(acc[j] * inv);
    }
    __syncthreads();                              // As/Bs ready (both steps)

    // MFMA over both steps, no further barriers
    int w = tid >> 6, lane = tid & 63, quad = lane >> 4, l16 = lane & 15;
    int wm = (w >> 1) * 32, wn = (w & 1) * 64;
    f32x4_t accf[2][4] = {};
#pragma unroll
    for (int t = 0; t < 2; ++t) {
        const unsigned short* as = As + t * ASZ;
        const unsigned short* bs = Bs + t * BSZ;
#pragma unroll
        for (int kq = 0; kq < 2; ++kq) {
            bhalf8_t af[2], bf[4];
#pragma unroll
            for (int i = 0; i < 2; ++i)
                af[i] = *reinterpret_cast<const bhalf8_t*>(
                    &as[(wm + i * 16 + l16) * BKp + kq * 32 + quad * 8]);
#pragma unroll
            for (int j = 0; j < 4; ++j)
                bf[j] = *reinterpret_cast<const bhalf8_t*>(
                    &bs[(wn + j * 16 + l16) * BKp + kq * 32 + quad * 8]);
#pragma unroll
            for (int i = 0; i < 2; ++i)
#pragma unroll
                for (int j = 0; j < 4; ++j)
                    accf[i][j] = __builtin_amdgcn_mfma_f32_16x16x32_f16(
                        __builtin_bit_cast(half8_t, af[i]), __builtin_bit_cast(half8_t, bf[j]),
                        accf[i][j], 0, 0, 0);
        }
    }

    unsigned short* Cp = Cpart + (long)ks * kS * 512;
#pragma unroll
    for (int i = 0; i < 2; ++i)
#pragma unroll
        for (int j = 0; j < 4; ++j)
#pragma unroll
            for (int r = 0; r < 4; ++r) {
                int m = bm + wm + i * 16 + quad * 4 + r;
                int n = bn + wn + j * 16 + l16;
                Cp[(long)m * 512 + n] = f2h(accf[i][j][r]);
            }
}

// ------ flash partial: 4 waves share one (h,z) K/V slice staged in LDS ----------
__global__ __launch_bounds__(256, 3)
void flash_part_k(const unsigned short* __restrict__ qb2, const unsigned short* __restrict__ kb2,
                  const unsigned short* __restrict__ vtb, const unsigned short* __restrict__ bmap,
                  unsigned short* __restrict__ po, float* __restrict__ pm, float* __restrict__ pl)
{
    constexpr int KP = 136;                 // padded row stride (16B-aligned rows)
    __shared__ __align__(16) unsigned short Klds[128 * KP];   // 34816 B; Ps later
    __shared__ __align__(16) unsigned short Vlds[64 * KP];    // 17408 B

    int tid = threadIdx.x;
    int w    = tid >> 6;
    int lane = tid & 63;
    int quad = lane >> 4, l16 = lane & 15;

    int wg  = blockIdx.x;                   // 1024 = 8 XCD chunks x 128
    int lin = (wg & 7) * 128 + (wg >> 3);   // bijective (1024 % 8 == 0)
    int qbg = lin & 15;
    int h   = (lin >> 4) & 7;
    int z   = lin >> 7;
    int qb  = qbg * 4 + w;
    int bm  = qb * 16;
    int k0  = z * 128;

    const unsigned short* Qh = qb2 + (long)h * 131072;
    const unsigned short* Kh = kb2 + (long)h * 131072;
    const unsigned short* Vh = vtb + (long)h * 65536;
    const unsigned short* Bm = bmap + (long)h * 1048576;

    // ---- cooperative stage: K (128 keys x 128), V (64 dims x 128 keys) ----
    {
        int kr = tid >> 1, kc = (tid & 1) * 64;
#pragma unroll
        for (int j = 0; j < 8; ++j)
            *reinterpret_cast<bhalf8_t*>(&Klds[kr * KP + kc + j * 8]) =
                *reinterpret_cast<const bhalf8_t*>(&Kh[(long)(k0 + kr) * 128 + kc + j * 8]);
        int vr = tid >> 2, vc = (tid & 3) * 32;
#pragma unroll
        for (int j = 0; j < 4; ++j)
            *reinterpret_cast<bhalf8_t*>(&Vlds[vr * KP + vc + j * 8]) =
                *reinterpret_cast<const bhalf8_t*>(&Vh[(long)vr * 1024 + k0 + vc + j * 8]);
    }

    // Q fragments (global, per-wave) + vectorized bias loads (permuted bmap)
    bhalf8_t aq[4];
#pragma unroll
    for (int kq = 0; kq < 4; ++kq)
        aq[kq] = *reinterpret_cast<const bhalf8_t*>(
            &Qh[(long)(bm + l16) * 128 + kq * 32 + quad * 8]);
    bhalf8_t bias8[4];
#pragma unroll
    for (int r = 0; r < 4; ++r) {
        int gm = bm + quad * 4 + r;
        bias8[r] = *reinterpret_cast<const bhalf8_t*>(
            &Bm[(long)gm * 1024 + z * 128 + l16 * 8]);
    }

    __syncthreads();                        // K/V staged

    f32x4_t sacc[8] = {};
#pragma unroll
    for (int kq = 0; kq < 4; ++kq) {
        bhalf8_t bk[8];
#pragma unroll
        for (int nb = 0; nb < 8; ++nb)
            bk[nb] = *reinterpret_cast<const bhalf8_t*>(
                &Klds[(nb * 16 + l16) * KP + kq * 32 + quad * 8]);
#pragma unroll
        for (int nb = 0; nb < 8; ++nb)
            sacc[nb] = __builtin_amdgcn_mfma_f32_16x16x32_f16(
                __builtin_bit_cast(half8_t, aq[kq]), __builtin_bit_cast(half8_t, bk[nb]),
                sacc[nb], 0, 0, 0);
    }

    float m_r[4] = {-3.0e38f, -3.0e38f, -3.0e38f, -3.0e38f};
#pragma unroll
    for (int nb = 0; nb < 8; ++nb)
#pragma unroll
        for (int r = 0; r < 4; ++r) {
            float bias = h2f((unsigned short)bias8[r][nb]);
            float s = fmaf(sacc[nb][r], 0.125f, bias);
            sacc[nb][r] = s;
            m_r[r] = fmaxf(m_r[r], s);
        }
#pragma unroll
    for (int r = 0; r < 4; ++r) {
        float m_ = m_r[r];
#pragma unroll
        for (int off = 1; off < 16; off <<= 1) m_ = fmaxf(m_, __shfl_xor(m_, off, 64));
        m_r[r] = m_;
    }

    __syncthreads();                        // all waves done reading Klds

    unsigned short* Ps = Klds + w * 16 * KP;   // per-wave 16 x KP region
    float l_r[4];
#pragma unroll
    for (int r = 0; r < 4; ++r) {
        int row = quad * 4 + r;
        float mN = m_r[r];
        float s_ = 0.f;
#pragma unroll
        for (int nb = 0; nb < 8; ++nb) {
            float p = __expf(sacc[nb][r] - mN);
            Ps[row * KP + nb * 16 + l16] = f2h(p * 16384.f);
            s_ += p;
        }
#pragma unroll
        for (int off = 1; off < 16; off <<= 1) s_ += __shfl_xor(s_, off, 64);
        l_r[r] = s_;
    }

    long sbase = (((long)z * 8 + h) * 64 + qb) * 16;
    if (l16 == 0) {
#pragma unroll
        for (int r = 0; r < 4; ++r) {
            pm[sbase + quad * 4 + r] = m_r[r];
            pl[sbase + quad * 4 + r] = l_r[r];
        }
    }

    f32x4_t oacc[4] = {};
#pragma unroll
    for (int kq2 = 0; kq2 < 4; ++kq2) {
        bhalf8_t ap = *reinterpret_cast<const bhalf8_t*>(&Ps[l16 * KP + kq2 * 32 + quad * 8]);
#pragma unroll
        for (int j2 = 0; j2 < 4; ++j2) {
            bhalf8_t bv = *reinterpret_cast<const bhalf8_t*>(
                &Vlds[(j2 * 16 + l16) * KP + kq2 * 32 + quad * 8]);
            oacc[j2] = __builtin_amdgcn_mfma_f32_16x16x32_f16(
                __builtin_bit_cast(half8_t, ap), __builtin_bit_cast(half8_t, bv),
                oacc[j2], 0, 0, 0);
        }
    }

    unsigned short* pob = po + sbase * 64;
#pragma unroll
    for (int j2 = 0; j2 < 4; ++j2)
#pragma unroll
        for (int r = 0; r < 4; ++r)
            pob[(quad * 4 + r) * 64 + j2 * 16 + l16] =
                f2h(oacc[j2][r] * (1.f / 16777216.f));
}

// ---------------- fused: f16 split-K reduce + bias + residual + LN + f16 xb -----
__global__ __launch_bounds__(256)
void add_ln_fused_k(const unsigned short* __restrict__ part, float* __restrict__ x,
                    const float* __restrict__ bias,
                    const float* __restrict__ g, const float* __restrict__ b,
                    unsigned short* __restrict__ xb, int splitk)
{
    __shared__ float sm[4];
    int row = blockIdx.x, t = threadIdx.x;
    const long MN = (long)kS * kD;
    float* xr = x + (long)row * kD;
    float s0 = 0.f, s1 = 0.f;
    const unsigned short* pr = part + (long)row * kD;
    for (int sl = 0; sl < splitk; ++sl) {
        s0 += h2f(pr[(long)sl * MN + t]);
        s1 += h2f(pr[(long)sl * MN + t + 256]);
    }
    s0 += bias[t] + xr[t];
    s1 += bias[t + 256] + xr[t + 256];
    float sum = wave_sum(s0 + s1);
    if ((t & 63) == 0) sm[t >> 6] = sum;
    __syncthreads();
    sum = sm[0] + sm[1] + sm[2] + sm[3];
    float mu = sum * (1.f / kD);
    float d0 = s0 - mu, d1 = s1 - mu;
    __syncthreads();
    float vs = wave_sum(d0 * d0 + d1 * d1);
    if ((t & 63) == 0) sm[t >> 6] = vs;
    __syncthreads();
    vs = sm[0] + sm[1] + sm[2] + sm[3];
    float rs = rsqrtf(vs * (1.f / kD) + 1e-5f);
    float o0 = fmaf(d0 * rs, g[t], b[t]);
    float o1 = fmaf(d1 * rs, g[t + 256], b[t + 256]);
    xr[t]       = o0;
    xr[t + 256] = o1;
    unsigned short* xrow = xb + (long)row * 512;
    xrow[t]       = f2h(o0);
    xrow[t + 256] = f2h(o1);
}

// ----- pool + classifier head, 3-phase: pool | spin-barrier | parallel h1 | c2 ---
__global__ __launch_bounds__(256)
void pool_head_k(const float* __restrict__ x, float* __restrict__ partial,
                 float* __restrict__ h1g, unsigned int* __restrict__ cnt2,
                 const float* __restrict__ c1w, const float* __restrict__ c1b,
                 const float* __restrict__ c2w, const float* __restrict__ c2b,
                 float* __restrict__ out)
{
    __shared__ float pooled[kD];
    __shared__ int flag;
    int t = threadIdx.x;
    int bid = blockIdx.x;
    int cb = bid & 1, rb = bid >> 1;   // 16 blocks: 2 col x 8 row
    int col = cb * 256 + t;
    float s = 0.f;
    for (int r = rb * 128; r < rb * 128 + 128; ++r) s += x[(long)r * kD + col];
    partial[rb * kD + col] = s;

    // ---- spin barrier across the 16 blocks (all co-resident) ----
    __threadfence();
    if (t == 0) {
        atomicAdd(&cnt2[0], 1u);
        while (atomicAdd(&cnt2[0], 0u) < 16u) {}
    }
    __syncthreads();
    __threadfence();

    // ---- full pooled vector (all blocks, redundant but tiny) ----
    {
        float p0 = 0.f, p1 = 0.f;
#pragma unroll
        for (int r = 0; r < 8; ++r) {
            p0 += partial[r * kD + t];
            p1 += partial[r * kD + t + 256];
        }
        pooled[t]       = p0 * (1.0f / kS);
        pooled[t + 256] = p1 * (1.0f / kS);
    }
    __syncthreads();

    // ---- h1 slice: block bid -> cols [bid*16, bid*16+16), 16 threads/col ----
    {
        int c = bid * 16 + (t >> 4);
        int sub = t & 15;
        float a = 0.f;
        for (int f = sub; f < kD; f += 16)
            a = fmaf(pooled[f], c1w[(long)f * 256 + c], a);
#pragma unroll
        for (int o = 1; o < 16; o <<= 1) a += __shfl_xor(a, o, 64);
        if (sub == 0) h1g[c] = fmaxf(a + c1b[c], 0.f);
    }

    // ---- last-arriver does c2 (tiny, parallel over 160 threads) ----
    __threadfence();
    if (t == 0) flag = (atomicAdd(&cnt2[1], 1u) == 15u);
    __syncthreads();
    if (!flag) return;
    __threadfence();

    if (t < 160) {
        int c = t >> 4, sub = t & 15;
        float a = 0.f;
        for (int f = sub; f < 256; f += 16)
            a = fmaf(h1g[f], c2w[(long)f * 10 + c], a);
#pragma unroll
        for (int o = 1; o < 16; o <<= 1) a += __shfl_xor(a, o, 64);
        if (sub == 0) out[c] = a + c2b[c];
    }
}

// ---------------- launch ----------------
extern "C" void kernel_launch(void* const* d_in, const int* in_sizes, int n_in,
                              void* d_out, int out_size, void* d_ws, size_t ws_size,
                              hipStream_t stream)
{
    (void)in_sizes; (void)n_in; (void)out_size; (void)ws_size;
    const float* features = (const float*)d_in[0];
    const float* positions= (const float*)d_in[1];
    const float* fb       = (const float*)d_in[2];
    const float* in_w     = (const float*)d_in[3];
    const float* in_b     = (const float*)d_in[4];
    const float* qw  = (const float*)d_in[5];
    const float* qb  = (const float*)d_in[6];
    const float* kw  = (const float*)d_in[7];
    const float* kb  = (const float*)d_in[8];
    const float* vw  = (const float*)d_in[9];
    const float* vb  = (const float*)d_in[10];
    const float* ow  = (const float*)d_in[11];
    const float* ob  = (const float*)d_in[12];
    const float* db1w= (const float*)d_in[13];
    const float* db1b= (const float*)d_in[14];
    const float* db2w= (const float*)d_in[15];
    const float* db2b= (const float*)d_in[16];
    const float* n1g = (const float*)d_in[17];
    const float* n1b = (const float*)d_in[18];
    const float* n2g = (const float*)d_in[19];
    const float* n2b = (const float*)d_in[20];
    const float* f1w = (const float*)d_in[21];
    const float* f1b = (const float*)d_in[22];
    const float* f2w = (const float*)d_in[23];
    const float* f2b = (const float*)d_in[24];
    const float* c1w = (const float*)d_in[25];
    const float* c1b = (const float*)d_in[26];
    const float* c2w = (const float*)d_in[27];
    const float* c2b = (const float*)d_in[28];

    float* ws = (float*)d_ws;
    const long SD = (long)kS * kD;            // 524288
    float* x      = ws;
    float* dist   = ws + 3 * SD;              // 2*SD
    float* part_f = ws + 5 * SD;              // scratch region (reused), 12*SD floats
    float* bpw    = ws + 17 * SD;
    float* Atab   = bpw + 256;
    float* Btab   = Atab + 2080;
    float* partial= Btab + 2080;

    // scratch carve (floats from part_f):
    unsigned short* part16 = (unsigned short*)part_f;
    unsigned short* po     = (unsigned short*)part_f;
    float* pmv = part_f + 2162688;
    float* plv = pmv + 65536;
    unsigned int* cnt2 = (unsigned int*)(plv + 65536);
    float* h1g = (float*)(cnt2 + 16);
    unsigned short* part16b = (unsigned short*)(part_f + 2294048);

    unsigned short* ub = (unsigned short*)(ws + 17 * SD + 8512);
    unsigned short* xb   = ub;                       // 1024*512 (f16)
    unsigned short* qb2  = ub   + 1048576;           // 8*1024*128 (2-seg)
    unsigned short* kb2  = qb2  + 1048576;
    unsigned short* vtb  = kb2  + 1048576;           // 512*1024 (f16)
    unsigned short* hb   = vtb  + 524288;            // 1024*2048
    unsigned short* qwb  = hb   + 2097152;           // 2 x 512*512
    unsigned short* kwb  = qwb  + 524288;
    unsigned short* vwb  = kwb  + 524288;
    unsigned short* owb  = vwb  + 524288;
    unsigned short* f1wb = owb  + 524288;            // 2 x 2048*512
    unsigned short* f2wb = f1wb + 2097152;           // 2 x 512*2048
    unsigned short* bmap = f2wb + 2097152;           // 8*1024*1024 f16 (permuted)

    // single merged preamble
    prep_k<<<7682, 256, 0, stream>>>(features, positions, fb, in_w, in_b, x, xb,
                                     dist, qw, kw, vw, ow, qwb, kwb, vwb, owb,
                                     f1w, f1wb, f2w, f2wb,
                                     db1w, db1b, db2w, db2b, bpw, Atab, Btab);

    for (int l = 0; l < 2; ++l) {
        // QKV GEMM (192 blocks) + biasmap (1024 blocks backfill) + cnt2 zeroing
        qkv_bias_k<<<1216, 256, 0, stream>>>(
            xb, qwb + l * 262144, kwb + l * 262144, vwb + l * 262144,
            qb + l * kD, kb + l * kD, vb + l * kD, qb2, kb2, vtb,
            dist, bpw + l * 128, Atab + l * 1040, Btab + l * 1040, bmap, cnt2);

        // fused attention: 4-wave blocks, K/V in LDS, vectorized bias reads
        flash_part_k<<<1024, 256, 0, stream>>>(
            qb2, kb2, vtb, bmap, po, pmv, plv);

        // O-proj with flash-merge fused into A-staging -> part16b
        bgemm_oproj_k<<<dim3(16, 4, 4), 256, 0, stream>>>(
            po, pmv, plv, owb + l * 262144, part16b);
        add_ln_fused_k<<<kS, 256, 0, stream>>>(
            part16b, x, ob + l * kD, n1g + l * kD, n1b + l * kD, xb, 4);

        // FFN1: no split-K (256 blocks), bias+relu -> hb f16
        bgemm_ffn1_k<<<dim3(16, 16), 256, 0, stream>>>(
            xb, f1wb + l * 1048576, f1b + l * kDFF, hb);

        // FFN2: K=2048, split-K x4 (256 blocks); reduce fused into add_ln
        bgemm_k<512><<<dim3(16, 4, 4), 256, 0, stream>>>(
            hb, f2wb + l * 1048576, 512, 2048, 2048, part16);
        add_ln_fused_k<<<kS, 256, 0, stream>>>(
            part16, x, f2b + l * kD, n2g + l * kD, n2b + l * kD, xb, 4);
    }

    // pool + parallel classifier head (16-block spin barrier, fences tiny at 16)
    pool_head_k<<<16, 256, 0, stream>>>(x, partial, h1g, cnt2,
                                        c1w, c1b, c2w, c2b, (float*)d_out);
}